// Round 1
// baseline (273.092 us; speedup 1.0000x reference)
//
#include <hip/hip_runtime.h>

// MultiScaleTrendDirectionLoss — B=32, T=8192, D=64, fp32 in, scalar fp32 out.
// Strategy: chunked EMA with decayed-carry warmup (K=96 steps re-warm; error
// (0.9)^96 ~ 4e-5 in EMA, negligible on final scalar vs 3.3e-3 threshold).
// lane = d channel -> 256B coalesced wave loads per time step.

namespace {
constexpr int BB  = 32;
constexpr int TT  = 8192;
constexpr int DD  = 64;
constexpr int CH  = 256;        // chunk length along T
constexpr int WU  = 96;         // warmup prefix length
constexpr int NCH = TT / CH;    // 32 chunks per sequence
static_assert(NCH == 32, "unit decode assumes 32 chunks");
// masked.mean(axis=1) divides by (T-1)=8191; final .mean() divides by B*D=2048
constexpr float INV_NORM = 1.0f / (8191.0f * 2048.0f);
}

__global__ void zero_out_kernel(float* o) { o[0] = 0.0f; }

__global__ __launch_bounds__(64) void ms_trend_loss_kernel(
    const float* __restrict__ pred, const float* __restrict__ targ,
    float* __restrict__ out) {
  const int unit = blockIdx.x;      // 0 .. BB*NCH-1
  const int b = unit >> 5;          // / NCH
  const int c = unit & 31;          // % NCH
  const int d = threadIdx.x;        // 0..63 == channel
  const int s = c * CH;             // chunk start t

  const float* p = pred + ((size_t)b * TT) * DD + d;
  const float* q = targ + ((size_t)b * TT) * DD + d;

  float pe0, pe1, pe2, te0, te1, te2;   // EMA states per alpha
  float acc = 0.0f;                     // weighted masked sum
  int t0;

  if (c == 0) {
    // exact start: ema_0 = x_0, first step at t=1
    float x = p[0], y = q[0];
    pe0 = pe1 = pe2 = x;
    te0 = te1 = te2 = y;
    t0 = 1;
  } else {
    // warm up from t = s-WU, pretending a fresh start there; carry error
    // decays by (1-alpha)^WU before the first accumulated step.
    const float* pw = p + (size_t)(s - WU) * DD;
    const float* qw = q + (size_t)(s - WU) * DD;
    float x = pw[0], y = qw[0];
    pe0 = pe1 = pe2 = x;
    te0 = te1 = te2 = y;
#pragma unroll 5
    for (int i = 1; i < WU; ++i) {
      float xx = pw[(size_t)i * DD];
      float yy = qw[(size_t)i * DD];
      pe0 += 0.1f * (xx - pe0);  te0 += 0.1f * (yy - te0);
      pe1 += 0.3f * (xx - pe1);  te1 += 0.3f * (yy - te1);
      pe2 += 0.5f * (xx - pe2);  te2 += 0.5f * (yy - te2);
    }
    t0 = s;
  }

  const int tend = s + CH;
#pragma unroll 8
  for (int t = t0; t < tend; ++t) {
    float xx = p[(size_t)t * DD];
    float yy = q[(size_t)t * DD];

    // alpha = 0.1, weight 0.5
    {
      float dp = 0.1f * (xx - pe0);          // pe_new - pe_old
      float dt = 0.1f * (yy - te0);
      pe0 += dp;  te0 += dt;
      bool mis = ((dp > 0.0f) != (dt > 0.0f)) || ((dp < 0.0f) != (dt < 0.0f));
      float e = pe0 - te0;
      if (mis) acc += 0.5f * (e * e);
    }
    // alpha = 0.3, weight 0.3
    {
      float dp = 0.3f * (xx - pe1);
      float dt = 0.3f * (yy - te1);
      pe1 += dp;  te1 += dt;
      bool mis = ((dp > 0.0f) != (dt > 0.0f)) || ((dp < 0.0f) != (dt < 0.0f));
      float e = pe1 - te1;
      if (mis) acc += 0.3f * (e * e);
    }
    // alpha = 0.5, weight 0.2
    {
      float dp = 0.5f * (xx - pe2);
      float dt = 0.5f * (yy - te2);
      pe2 += dp;  te2 += dt;
      bool mis = ((dp > 0.0f) != (dt > 0.0f)) || ((dp < 0.0f) != (dt < 0.0f));
      float e = pe2 - te2;
      if (mis) acc += 0.2f * (e * e);
    }
  }

  // wave-64 reduction, one atomic per wave
#pragma unroll
  for (int off = 32; off > 0; off >>= 1) acc += __shfl_down(acc, off);
  if (d == 0) atomicAdd(out, acc * INV_NORM);
}

extern "C" void kernel_launch(void* const* d_in, const int* in_sizes, int n_in,
                              void* d_out, int out_size, void* d_ws, size_t ws_size,
                              hipStream_t stream) {
  (void)in_sizes; (void)n_in; (void)out_size; (void)d_ws; (void)ws_size;
  const float* pred = (const float*)d_in[0];
  const float* targ = (const float*)d_in[1];
  float* out = (float*)d_out;

  zero_out_kernel<<<1, 1, 0, stream>>>(out);
  ms_trend_loss_kernel<<<BB * NCH, 64, 0, stream>>>(pred, targ, out);
}

// Round 2
// 201.660 us; speedup vs baseline: 1.3542x; 1.3542x over previous
//
#include <hip/hip_runtime.h>

// MultiScaleTrendDirectionLoss — B=32, T=8192, D=64, fp32 in, scalar fp32 out.
// R2: latency-bound fix. CH=64/WU=64 quadruples wave count (4 waves/SIMD),
// and an explicit 8-step batched load + prefetch double-buffer amortizes
// memory latency over 16 outstanding loads per wave.
// Carry error after 64-step warmup: (0.9)^64 ~ 1.2e-3 -> ~1e-5 on the final
// mean, far below the 3.26e-3 threshold (R1 with (0.9)^96 gave absmax 0.0).

namespace {
constexpr int BB  = 32;
constexpr int TT  = 8192;
constexpr int DD  = 64;
constexpr int CH  = 64;         // chunk length along T
constexpr int WU  = 64;         // warmup prefix length (multiple of 8)
constexpr int NCH = TT / CH;    // 128 chunks per sequence
constexpr int WPB = 4;          // waves per block (256 threads)
// masked.mean(axis=1) divides by (T-1)=8191; final .mean() divides by B*D=2048
constexpr float INV_NORM = 1.0f / (8191.0f * 2048.0f);
}

__global__ void zero_out_kernel(float* o) { o[0] = 0.0f; }

template <bool ACC>
__device__ __forceinline__ void ema_step(float xx, float yy,
    float& pe0, float& te0, float& pe1, float& te1, float& pe2, float& te2,
    float& acc) {
  {
    float dp = 0.1f * (xx - pe0), dt = 0.1f * (yy - te0);
    pe0 += dp;  te0 += dt;
    if (ACC) {
      bool mis = ((dp > 0.0f) != (dt > 0.0f)) || ((dp < 0.0f) != (dt < 0.0f));
      float e = pe0 - te0;
      if (mis) acc += 0.5f * (e * e);
    }
  }
  {
    float dp = 0.3f * (xx - pe1), dt = 0.3f * (yy - te1);
    pe1 += dp;  te1 += dt;
    if (ACC) {
      bool mis = ((dp > 0.0f) != (dt > 0.0f)) || ((dp < 0.0f) != (dt < 0.0f));
      float e = pe1 - te1;
      if (mis) acc += 0.3f * (e * e);
    }
  }
  {
    float dp = 0.5f * (xx - pe2), dt = 0.5f * (yy - te2);
    pe2 += dp;  te2 += dt;
    if (ACC) {
      bool mis = ((dp > 0.0f) != (dt > 0.0f)) || ((dp < 0.0f) != (dt < 0.0f));
      float e = pe2 - te2;
      if (mis) acc += 0.2f * (e * e);
    }
  }
}

__global__ __launch_bounds__(256) void ms_trend_loss_kernel(
    const float* __restrict__ pred, const float* __restrict__ targ,
    float* __restrict__ out) {
  const int lane = threadIdx.x & 63;
  const int wave = threadIdx.x >> 6;
  const int unit = blockIdx.x * WPB + wave;   // 0 .. BB*NCH-1
  const int b = unit >> 7;                    // / NCH (NCH=128)
  const int c = unit & 127;                   // % NCH
  const int s = c * CH;
  const int start = (c == 0) ? 0 : (s - WU);
  const int nw    = (c == 0) ? 0 : WU;        // warmup steps (wave-uniform)

  const float* p = pred + ((size_t)b * TT + start) * DD + lane;
  const float* q = targ + ((size_t)b * TT + start) * DD + lane;

  // init state at t=start; the first processed step re-sees the same value,
  // giving dp=dt=0 -> no state change, no mask hit (matches ema_0 = x_0).
  float x0 = p[0], y0 = q[0];
  float pe0 = x0, pe1 = x0, pe2 = x0;
  float te0 = y0, te1 = y0, te2 = y0;
  float acc = 0.0f;

  // ---- warmup: nw steps, batched by 8 (no accumulation) ----
  for (int bt = 0; bt < nw; bt += 8) {
    float xs[8], ys[8];
#pragma unroll
    for (int i = 0; i < 8; ++i) {
      xs[i] = p[(size_t)(bt + i) * DD];
      ys[i] = q[(size_t)(bt + i) * DD];
    }
#pragma unroll
    for (int i = 0; i < 8; ++i)
      ema_step<false>(xs[i], ys[i], pe0, te0, pe1, te1, pe2, te2, acc);
  }
  p += (size_t)nw * DD;
  q += (size_t)nw * DD;

  // ---- main: CH steps, software-pipelined (prefetch next 8 during compute) ----
  float xs[8], ys[8];
#pragma unroll
  for (int i = 0; i < 8; ++i) {
    xs[i] = p[(size_t)i * DD];
    ys[i] = q[(size_t)i * DD];
  }
  for (int bt = 8; bt < CH; bt += 8) {
    float xn[8], yn[8];
#pragma unroll
    for (int i = 0; i < 8; ++i) {
      xn[i] = p[(size_t)(bt + i) * DD];
      yn[i] = q[(size_t)(bt + i) * DD];
    }
#pragma unroll
    for (int i = 0; i < 8; ++i)
      ema_step<true>(xs[i], ys[i], pe0, te0, pe1, te1, pe2, te2, acc);
#pragma unroll
    for (int i = 0; i < 8; ++i) { xs[i] = xn[i]; ys[i] = yn[i]; }
  }
#pragma unroll
  for (int i = 0; i < 8; ++i)
    ema_step<true>(xs[i], ys[i], pe0, te0, pe1, te1, pe2, te2, acc);

  // wave-64 reduction, one atomic per wave
#pragma unroll
  for (int off = 32; off > 0; off >>= 1) acc += __shfl_down(acc, off);
  if (lane == 0) atomicAdd(out, acc * INV_NORM);
}

extern "C" void kernel_launch(void* const* d_in, const int* in_sizes, int n_in,
                              void* d_out, int out_size, void* d_ws, size_t ws_size,
                              hipStream_t stream) {
  (void)in_sizes; (void)n_in; (void)out_size; (void)d_ws; (void)ws_size;
  const float* pred = (const float*)d_in[0];
  const float* targ = (const float*)d_in[1];
  float* out = (float*)d_out;

  zero_out_kernel<<<1, 1, 0, stream>>>(out);
  ms_trend_loss_kernel<<<BB * NCH / WPB, 256, 0, stream>>>(pred, targ, out);
}

// Round 4
// 170.613 us; speedup vs baseline: 1.6007x; 1.1820x over previous
//
#include <hip/hip_runtime.h>

// MultiScaleTrendDirectionLoss — B=32, T=8192, D=64, fp32 in, scalar fp32 out.
// R4 = R3 with the OOB fix: warmup start clamped to 0 (R3 read pred[-32*64]
// for chunk c=1 -> core dump). CH=32/WU=64 -> 8192 waves (32/CU = HW max).
// Single software-pipelined loop covers warmup+main with a wave-uniform ACC
// gate per 8-step batch. Block-level LDS reduce -> 1 atomic per 256-thr block.
// Warmup re-reads (3x logical traffic) are served by the 256 MB L3; HBM sees
// only the compulsory ~134 MB (confirmed R2: FETCH_SIZE == input bytes).

namespace {
constexpr int BB  = 32;
constexpr int TT  = 8192;
constexpr int DD  = 64;
constexpr int CH  = 32;         // chunk length along T
constexpr int WU  = 64;         // warmup prefix (multiple of 8)
constexpr int NCH = TT / CH;    // 256 chunks per sequence
constexpr int WPB = 4;          // waves per block (256 threads)
// masked.mean(axis=1) divides by (T-1)=8191; final .mean() divides by B*D=2048
constexpr float INV_NORM = 1.0f / (8191.0f * 2048.0f);
}

__global__ void zero_out_kernel(float* o) { o[0] = 0.0f; }

template <bool ACC>
__device__ __forceinline__ void ema_step(float xx, float yy,
    float& pe0, float& te0, float& pe1, float& te1, float& pe2, float& te2,
    float& acc) {
  {
    float dp = 0.1f * (xx - pe0), dt = 0.1f * (yy - te0);
    pe0 += dp;  te0 += dt;
    if (ACC) {
      bool mis = ((dp > 0.0f) != (dt > 0.0f)) || ((dp < 0.0f) != (dt < 0.0f));
      float e = pe0 - te0;
      if (mis) acc += 0.5f * (e * e);
    }
  }
  {
    float dp = 0.3f * (xx - pe1), dt = 0.3f * (yy - te1);
    pe1 += dp;  te1 += dt;
    if (ACC) {
      bool mis = ((dp > 0.0f) != (dt > 0.0f)) || ((dp < 0.0f) != (dt < 0.0f));
      float e = pe1 - te1;
      if (mis) acc += 0.3f * (e * e);
    }
  }
  {
    float dp = 0.5f * (xx - pe2), dt = 0.5f * (yy - te2);
    pe2 += dp;  te2 += dt;
    if (ACC) {
      bool mis = ((dp > 0.0f) != (dt > 0.0f)) || ((dp < 0.0f) != (dt < 0.0f));
      float e = pe2 - te2;
      if (mis) acc += 0.2f * (e * e);
    }
  }
}

__global__ __launch_bounds__(256, 8) void ms_trend_loss_kernel(
    const float* __restrict__ pred, const float* __restrict__ targ,
    float* __restrict__ out) {
  const int lane = threadIdx.x & 63;
  const int wave = threadIdx.x >> 6;
  const int unit = blockIdx.x * WPB + wave;   // 0 .. BB*NCH-1
  const int b = unit >> 8;                    // / NCH (NCH=256)
  const int c = unit & 255;                   // % NCH
  const int s = c * CH;
  const int start0 = s - WU;
  const int start = start0 < 0 ? 0 : start0;  // CLAMP (R3 bug: went negative)
  const int nw    = s - start;                // warmup steps; multiple of 32
  const int total = nw + CH;                  // multiple of 8, wave-uniform

  const float* p = pred + ((size_t)b * TT + start) * DD + lane;
  const float* q = targ + ((size_t)b * TT + start) * DD + lane;

  // init state at t=start; the first processed step re-sees the same value,
  // giving dp=dt=0 -> no state change, no mask hit (matches ema_0 = x_0).
  float x0 = p[0], y0 = q[0];
  float pe0 = x0, pe1 = x0, pe2 = x0;
  float te0 = y0, te1 = y0, te2 = y0;
  float acc = 0.0f;

  // ---- software-pipelined loop over all steps (warmup gated off) ----
  float xs[8], ys[8];
#pragma unroll
  for (int i = 0; i < 8; ++i) {
    xs[i] = p[(size_t)i * DD];
    ys[i] = q[(size_t)i * DD];
  }
  for (int bt = 0; bt < total - 8; bt += 8) {
    float xn[8], yn[8];
#pragma unroll
    for (int i = 0; i < 8; ++i) {
      xn[i] = p[(size_t)(bt + 8 + i) * DD];
      yn[i] = q[(size_t)(bt + 8 + i) * DD];
    }
    if (bt >= nw) {
#pragma unroll
      for (int i = 0; i < 8; ++i)
        ema_step<true>(xs[i], ys[i], pe0, te0, pe1, te1, pe2, te2, acc);
    } else {
#pragma unroll
      for (int i = 0; i < 8; ++i)
        ema_step<false>(xs[i], ys[i], pe0, te0, pe1, te1, pe2, te2, acc);
    }
#pragma unroll
    for (int i = 0; i < 8; ++i) { xs[i] = xn[i]; ys[i] = yn[i]; }
  }
#pragma unroll
  for (int i = 0; i < 8; ++i)
    ema_step<true>(xs[i], ys[i], pe0, te0, pe1, te1, pe2, te2, acc);

  // wave-64 shuffle reduce -> per-block LDS reduce -> 1 atomic per block
#pragma unroll
  for (int off = 32; off > 0; off >>= 1) acc += __shfl_down(acc, off);
  __shared__ float sred[WPB];
  if (lane == 0) sred[wave] = acc;
  __syncthreads();
  if (threadIdx.x == 0) {
    float t = sred[0] + sred[1] + sred[2] + sred[3];
    atomicAdd(out, t * INV_NORM);
  }
}

extern "C" void kernel_launch(void* const* d_in, const int* in_sizes, int n_in,
                              void* d_out, int out_size, void* d_ws, size_t ws_size,
                              hipStream_t stream) {
  (void)in_sizes; (void)n_in; (void)out_size; (void)d_ws; (void)ws_size;
  const float* pred = (const float*)d_in[0];
  const float* targ = (const float*)d_in[1];
  float* out = (float*)d_out;

  zero_out_kernel<<<1, 1, 0, stream>>>(out);
  ms_trend_loss_kernel<<<BB * NCH / WPB, 256, 0, stream>>>(pred, targ, out);
}